// Round 2
// baseline (10800.920 us; speedup 1.0000x reference)
//
#include <hip/hip_runtime.h>
#include <hip/hip_bf16.h>
#include <cstddef>

// Problem dims (fixed by the reference)
constexpr int B = 32, T = 128, S = 128, D = 512, H = 512, V = 16000;
constexpr int G4H = 4 * H;     // 2048
constexpr int TB = T * B;      // 4096

typedef __bf16 bf16x8 __attribute__((ext_vector_type(8)));
typedef float  f32x4  __attribute__((ext_vector_type(4)));

__device__ __forceinline__ float tanh_fast(float x) {
    return 1.0f - 2.0f / (__expf(2.0f * x) + 1.0f);
}
__device__ __forceinline__ float sigmoid_fast(float x) {
    return 1.0f / (1.0f + __expf(-x));
}
__device__ __forceinline__ unsigned short f2bf_rn(float x) {
    unsigned u = __float_as_uint(x);
    unsigned r = (u + 0x7FFFu + ((u >> 16) & 1u)) >> 16;
    return (unsigned short)r;
}
__device__ __forceinline__ float bf2f(unsigned short h) {
    return __uint_as_float(((unsigned)h) << 16);
}
__device__ __forceinline__ void async16(const void* g, void* l) {
    __builtin_amdgcn_global_load_lds(
        (const __attribute__((address_space(1))) void*)g,
        (__attribute__((address_space(3))) void*)l, 16, 0, 0);
}

// ---------------------------------------------------------------------------
// Embedding gather
// ---------------------------------------------------------------------------
__global__ __launch_bounds__(128) void gather_emb(
    const int* __restrict__ x, const int* __restrict__ teacher,
    const float* __restrict__ embed, float* __restrict__ emb_g)
{
    int r = blockIdx.x;            // t*B + b
    int t = r >> 5, b = r & 31;
    int tok = (t == 0) ? x[b * T] : teacher[b * T + t - 1];
    const float4* src = (const float4*)(embed + (size_t)tok * D);
    float4* dst = (float4*)(emb_g + (size_t)r * D);
    dst[threadIdx.x] = src[threadIdx.x];
}

// ---------------------------------------------------------------------------
// Generic fp32 tiled GEMM (kept for gates/keys/Q — small fraction of runtime)
// ---------------------------------------------------------------------------
template<bool BT>
__global__ __launch_bounds__(256) void gemm_kernel(
    const float* __restrict__ A, const float* __restrict__ Bm,
    const float* __restrict__ bias1, const float* __restrict__ bias2,
    float* __restrict__ C, int M, int N, int K)
{
    constexpr int BM = 128, BN = 64, BK = 16;
    __shared__ float As[BK][BM + 4];
    __shared__ float Bs[BK][BN + 4];

    int tid = threadIdx.x;
    int m0 = blockIdx.y * BM, n0 = blockIdx.x * BN;
    int tx = tid & 15, ty = tid >> 4;
    int ar = tid >> 2;
    int ak = (tid & 3) * 4;
    int bkk = tid >> 4;
    int bnn = (tid & 15) * 4;

    float acc[8][4];
    #pragma unroll
    for (int i = 0; i < 8; ++i)
        #pragma unroll
        for (int j = 0; j < 4; ++j) acc[i][j] = 0.f;

    for (int k0 = 0; k0 < K; k0 += BK) {
        #pragma unroll
        for (int rr = 0; rr < 2; ++rr) {
            int row = ar + rr * 64;
            float4 v = *(const float4*)(A + (size_t)(m0 + row) * K + k0 + ak);
            As[ak + 0][row] = v.x; As[ak + 1][row] = v.y;
            As[ak + 2][row] = v.z; As[ak + 3][row] = v.w;
        }
        if (BT) {
            float4 v = *(const float4*)(Bm + (size_t)(n0 + ar) * K + k0 + ak);
            Bs[ak + 0][ar] = v.x; Bs[ak + 1][ar] = v.y;
            Bs[ak + 2][ar] = v.z; Bs[ak + 3][ar] = v.w;
        } else {
            float4 v = *(const float4*)(Bm + (size_t)(k0 + bkk) * N + n0 + bnn);
            *(float4*)&Bs[bkk][bnn] = v;
        }
        __syncthreads();

        #pragma unroll
        for (int kk = 0; kk < BK; ++kk) {
            float a[8], bb[4];
            *(float4*)&a[0] = *(const float4*)&As[kk][ty * 8];
            *(float4*)&a[4] = *(const float4*)&As[kk][ty * 8 + 4];
            *(float4*)&bb[0] = *(const float4*)&Bs[kk][tx * 4];
            #pragma unroll
            for (int i = 0; i < 8; ++i)
                #pragma unroll
                for (int j = 0; j < 4; ++j)
                    acc[i][j] = fmaf(a[i], bb[j], acc[i][j]);
        }
        __syncthreads();
    }

    float bs[4];
    #pragma unroll
    for (int j = 0; j < 4; ++j) {
        float v = 0.f;
        if (bias1) v += bias1[n0 + tx * 4 + j];
        if (bias2) v += bias2[n0 + tx * 4 + j];
        bs[j] = v;
    }
    #pragma unroll
    for (int i = 0; i < 8; ++i) {
        int row = m0 + ty * 8 + i;
        float* crow = C + (size_t)row * N;
        float4 o;
        o.x = acc[i][0] + bs[0]; o.y = acc[i][1] + bs[1];
        o.z = acc[i][2] + bs[2]; o.w = acc[i][3] + bs[3];
        *(float4*)(crow + n0 + tx * 4) = o;
    }
}

// ---------------------------------------------------------------------------
// Persistent LSTM: 256 blocks (1/CU), 512 threads. W_hh rows cached in LDS
// once; hx staged from global per step; manual grid barrier between steps.
// Block bk owns h = {2bk, 2bk+1} -> 8 gate rows. Threads: (b=32) x (r=8) x (kh=2).
// ---------------------------------------------------------------------------
__global__ __launch_bounds__(512, 2) void lstm_persistent(
    const float* __restrict__ gates_ih, const float* __restrict__ W_hh,
    float* __restrict__ Hseq, unsigned int* __restrict__ bar)
{
    __shared__ float Wl[8][512];     // 16 KB
    __shared__ float hxl[32][516];   // 66 KB (pad 4 floats -> reduced conflicts)
    __shared__ float gl2[2][8][32];  // partial gates (kh halves)
    __shared__ float cxl[2][32];

    int tid = threadIdx.x, bk = blockIdx.x;

    // preload W rows: 8 rows x 512 floats = 1024 float4
    for (int i = tid; i < 1024; i += 512) {
        int r = i >> 7, k4 = i & 127;
        int grow = (r >> 1) * 512 + bk * 2 + (r & 1);
        ((float4*)&Wl[r][0])[k4] = ((const float4*)(W_hh + (size_t)grow * 512))[k4];
    }
    if (tid < 64) cxl[tid >> 5][tid & 31] = 0.f;
    __syncthreads();

    int b = tid & 31, r = (tid >> 5) & 7, kh = tid >> 8;
    int grow_my = (r >> 1) * 512 + bk * 2 + (r & 1);

    for (int t = 0; t < 128; ++t) {
        // stage h_{t-1} -> hxl [b][k]
        if (t == 0) {
            float4 zz = make_float4(0.f, 0.f, 0.f, 0.f);
            for (int i = tid; i < 4096; i += 512) {
                int bb = i >> 7, k4 = i & 127;
                *(float4*)&hxl[bb][k4 * 4] = zz;
            }
        } else {
            const float4* Hp = (const float4*)(Hseq + (size_t)(t - 1) * 32 * 512);
            for (int i = tid; i < 4096; i += 512) {
                int bb = i >> 7, k4 = i & 127;
                *(float4*)&hxl[bb][k4 * 4] = Hp[bb * 128 + k4];
            }
        }
        __syncthreads();

        float gih = (kh == 0) ? gates_ih[((size_t)t * 32 + b) * 2048 + grow_my] : 0.f;
        const float4* wr = (const float4*)&Wl[r][0];
        const float4* xr = (const float4*)&hxl[b][0];
        float a0 = 0.f, a1 = 0.f, a2 = 0.f, a3 = 0.f;
        int k4base = kh * 64;
        #pragma unroll 8
        for (int k4 = 0; k4 < 64; ++k4) {
            float4 w = wr[k4base + k4], xv = xr[k4base + k4];
            a0 = fmaf(w.x, xv.x, a0); a1 = fmaf(w.y, xv.y, a1);
            a2 = fmaf(w.z, xv.z, a2); a3 = fmaf(w.w, xv.w, a3);
        }
        gl2[kh][r][b] = (a0 + a1) + (a2 + a3) + gih;
        __syncthreads();

        if (tid < 64) {
            int hl = tid >> 5, bb = tid & 31;
            float gi = gl2[0][0 + hl][bb] + gl2[1][0 + hl][bb];
            float gf = gl2[0][2 + hl][bb] + gl2[1][2 + hl][bb];
            float gg = gl2[0][4 + hl][bb] + gl2[1][4 + hl][bb];
            float go = gl2[0][6 + hl][bb] + gl2[1][6 + hl][bb];
            float i_ = sigmoid_fast(gi), f_ = sigmoid_fast(gf), o_ = sigmoid_fast(go);
            float c = fmaf(f_, cxl[hl][bb], i_ * tanh_fast(gg));
            cxl[hl][bb] = c;
            float h = o_ * tanh_fast(c);
            Hseq[((size_t)t * 32 + bb) * 512 + bk * 2 + hl] = h;
        }

        if (t != 127) {
            __threadfence();               // release: Hseq writes device-visible
            __syncthreads();
            if (tid == 0) {
                atomicAdd(bar, 1u);
                unsigned target = 256u * (unsigned)(t + 1);
                while (__hip_atomic_load(bar, __ATOMIC_ACQUIRE,
                                         __HIP_MEMORY_SCOPE_AGENT) < target)
                    __builtin_amdgcn_s_sleep(1);
            }
            __syncthreads();
            __threadfence();               // acquire: invalidate stale cache lines
        }
    }
}

// ---------------------------------------------------------------------------
// Fused attention (unchanged from round 1)
// ---------------------------------------------------------------------------
__global__ __launch_bounds__(256) void attn_fused(
    const float* __restrict__ Q, const float* __restrict__ keys,
    const float* __restrict__ z, const float* __restrict__ v_att,
    const float* __restrict__ Hseq, float* __restrict__ U)
{
    __shared__ float qv[512], va[512], ph[256], sc[128], red[128];
    int r = blockIdx.x, b = r & 31, tid = threadIdx.x;

    if (tid < 128) ((float4*)qv)[tid] = ((const float4*)(Q + (size_t)r * H))[tid];
    else           ((float4*)va)[tid - 128] = ((const float4*)v_att)[tid - 128];
    __syncthreads();

    int s = tid >> 1, half = tid & 1;
    const float4* k4 = (const float4*)(keys + ((size_t)b * S + s) * H + half * 256);
    const float4* q4p = (const float4*)(qv + half * 256);
    const float4* v4p = (const float4*)(va + half * 256);
    float acc = 0.f;
    #pragma unroll 4
    for (int i = 0; i < 64; ++i) {
        float4 kv = k4[i], q4 = q4p[i], v4 = v4p[i];
        acc += tanh_fast(kv.x + q4.x) * v4.x + tanh_fast(kv.y + q4.y) * v4.y
             + tanh_fast(kv.z + q4.z) * v4.z + tanh_fast(kv.w + q4.w) * v4.w;
    }
    ph[tid] = acc;
    __syncthreads();
    if (tid < 128) { float v = ph[2 * tid] + ph[2 * tid + 1]; sc[tid] = v; red[tid] = v; }
    __syncthreads();
    for (int st = 64; st > 0; st >>= 1) {
        if (tid < st) red[tid] = fmaxf(red[tid], red[tid + st]);
        __syncthreads();
    }
    float mx = red[0];
    __syncthreads();
    if (tid < 128) { float e = __expf(sc[tid] - mx); sc[tid] = e; red[tid] = e; }
    __syncthreads();
    for (int st = 64; st > 0; st >>= 1) {
        if (tid < st) red[tid] += red[tid + st];
        __syncthreads();
    }
    float inv = 1.0f / red[0];

    const float* zb = z + (size_t)b * S * H;
    int h1 = tid, h2 = tid + 256;
    float c1 = 0.f, c2 = 0.f;
    #pragma unroll 4
    for (int s2 = 0; s2 < S; ++s2) {
        float wgt = sc[s2];
        c1 = fmaf(wgt, zb[(size_t)s2 * H + h1], c1);
        c2 = fmaf(wgt, zb[(size_t)s2 * H + h2], c2);
    }
    float* urow = U + (size_t)r * (2 * H);
    urow[h1] = c1 * inv;
    urow[h2] = c2 * inv;
    urow[H + h1] = Hseq[(size_t)r * H + h1];
    urow[H + h2] = Hseq[(size_t)r * H + h2];
}

// ---------------------------------------------------------------------------
// fp32 -> split bf16 (hi|lo) conversion: src [rows][1024] f32 -> dst [rows][2048]
// ---------------------------------------------------------------------------
__global__ __launch_bounds__(256) void conv_split(
    const float* __restrict__ src, unsigned short* __restrict__ dst, long total4)
{
    for (long i = (long)blockIdx.x * 256 + threadIdx.x; i < total4;
         i += (long)gridDim.x * 256) {
        long rr = i >> 8; int c4 = (int)(i & 255) * 4;
        float4 v = ((const float4*)src)[i];
        ushort4 h, l;
        h.x = f2bf_rn(v.x); l.x = f2bf_rn(v.x - bf2f(h.x));
        h.y = f2bf_rn(v.y); l.y = f2bf_rn(v.y - bf2f(h.y));
        h.z = f2bf_rn(v.z); l.z = f2bf_rn(v.z - bf2f(h.z));
        h.w = f2bf_rn(v.w); l.w = f2bf_rn(v.w - bf2f(h.w));
        *(ushort4*)(dst + rr * 2048 + c4) = h;
        *(ushort4*)(dst + rr * 2048 + 1024 + c4) = l;
    }
}

// ---------------------------------------------------------------------------
// bf16 MFMA projection GEMM with split-precision slabs.
// Logical K=3072: slab0 Ahi*Bhi, slab1 Alo*Bhi, slab2 Ahi*Blo.
// A' [4096][2048] = [Ahi|Alo]; B' [16000][2048] = [Bhi|Blo].
//   A col = k<2048 ? k : k-2048 ;  B col = k<1024 ? k : k-1024.
// 128x128 tile, BK=32, 4 waves (2x2 of 64x64), 16x16x32 bf16 MFMA,
// global_load_lds width-16, XCD-swizzled n-major grid. REMAP epilogue + bias.
// ---------------------------------------------------------------------------
__global__ __launch_bounds__(256) void gemm_mfma_proj(
    const unsigned short* __restrict__ Ab,   // [4096][2048] bf16 bits
    const unsigned short* __restrict__ Bb,   // [16000][2048] bf16 bits
    const float* __restrict__ bias, float* __restrict__ out)
{
    __shared__ unsigned short As[128 * 32];
    __shared__ unsigned short Bs[128 * 32];

    int tid = threadIdx.x;
    int wid = tid >> 6, lane = tid & 63;
    int wm = wid >> 1, wn = wid & 1;
    int lr = lane & 15, lk = lane >> 4;

    int wg = blockIdx.x;                       // 4000 blocks = 8 * 500
    int swz = (wg & 7) * 500 + (wg >> 3);      // XCD-contiguous chunks
    int m_t = swz & 31, n_t = swz >> 5;        // n-major: neighbors share B-panels
    int m0 = m_t * 128, n0 = n_t * 128;

    f32x4 acc[4][4] = {};

    int crow = lane >> 2;           // row within 16-row chunk
    int ccol = (lane & 3) * 8;      // bf16 col offset within 32-col tile

    for (int kt = 0; kt < 96; ++kt) {
        int k0 = kt * 32;
        int kA = (k0 < 2048) ? k0 : k0 - 2048;
        int kB = (k0 < 1024) ? k0 : k0 - 1024;
        #pragma unroll
        for (int c = 0; c < 2; ++c) {
            int ch = wid * 2 + c;                    // chunk 0..7
            int row = ch * 16 + crow;                // 0..127
            const unsigned short* ga = Ab + (size_t)(m0 + row) * 2048 + kA + ccol;
            async16(ga, &As[ch * 512]);
            const unsigned short* gb = Bb + (size_t)(n0 + row) * 2048 + kB + ccol;
            async16(gb, &Bs[ch * 512]);
        }
        __syncthreads();

        bf16x8 a[4], bfr[4];
        #pragma unroll
        for (int f = 0; f < 4; ++f) {
            a[f]   = *(const bf16x8*)&As[(wm * 64 + f * 16 + lr) * 32 + lk * 8];
            bfr[f] = *(const bf16x8*)&Bs[(wn * 64 + f * 16 + lr) * 32 + lk * 8];
        }
        #pragma unroll
        for (int i = 0; i < 4; ++i)
            #pragma unroll
            for (int j = 0; j < 4; ++j)
                acc[i][j] = __builtin_amdgcn_mfma_f32_16x16x32_bf16(
                    a[i], bfr[j], acc[i][j], 0, 0, 0);
        __syncthreads();
    }

    // epilogue: C/D layout col=lane&15, row=(lane>>4)*4+reg  (m89/m91 verified)
    #pragma unroll
    for (int j = 0; j < 4; ++j) {
        int col = n0 + wn * 64 + j * 16 + lr;
        float bv = bias[col];
        #pragma unroll
        for (int i = 0; i < 4; ++i) {
            #pragma unroll
            for (int q = 0; q < 4; ++q) {
                int row = m0 + wm * 64 + i * 16 + lk * 4 + q;   // r = t*32+b
                int t = row >> 5, b = row & 31;
                out[((size_t)b * 128 + t) * 16000 + col] = acc[i][j][q] + bv;
            }
        }
    }
}

// ---------------------------------------------------------------------------
extern "C" void kernel_launch(void* const* d_in, const int* in_sizes, int n_in,
                              void* d_out, int out_size, void* d_ws, size_t ws_size,
                              hipStream_t stream)
{
    const int*   x       = (const int*)  d_in[0];
    const int*   teacher = (const int*)  d_in[1];
    const float* z       = (const float*)d_in[2];
    const float* embed   = (const float*)d_in[3];
    const float* W_ih    = (const float*)d_in[4];
    const float* b_ih    = (const float*)d_in[5];
    const float* W_hh    = (const float*)d_in[6];
    const float* b_hh    = (const float*)d_in[7];
    const float* Wq      = (const float*)d_in[8];
    const float* Wk      = (const float*)d_in[9];
    const float* v_att   = (const float*)d_in[10];
    const float* W_proj  = (const float*)d_in[11];
    const float* b_proj  = (const float*)d_in[12];
    float* out = (float*)d_out;

    // workspace layout (float offsets). Bconv overlays [0 .. 65.5MB) which is
    // dead (emb_g/gates_ih/keys/Qbuf/Hseq) by the time conv_split(W) runs.
    float* ws = (float*)d_ws;
    float* emb_g    = ws;                        // 2,097,152 f
    float* gates_ih = ws + 2097152;              // 8,388,608 f
    float* keys     = ws + 10485760;             // 2,097,152 f
    float* Qbuf     = ws + 12582912;             // 2,097,152 f
    float* Hseq     = ws + 14680064;             // 2,097,152 f
    float* Ubuf     = ws + 16777216;             // 4,194,304 f (ends 20,971,520)
    unsigned short* Aconv = (unsigned short*)(ws + 20971520);  // 16.8 MB
    unsigned short* Bconv = (unsigned short*)ws;               // 65.5 MB overlay
    unsigned int*   bar   = (unsigned int*)(ws + 25165824);

    hipMemsetAsync(bar, 0, sizeof(unsigned int), stream);

    gather_emb<<<TB, 128, 0, stream>>>(x, teacher, embed, emb_g);

    // gates_ih = emb_g @ W_ih^T + (b_ih + b_hh)
    gemm_kernel<true><<<dim3(G4H / 64, TB / 128), 256, 0, stream>>>(
        emb_g, W_ih, b_ih, b_hh, gates_ih, TB, G4H, D);

    // keys = z @ Wk
    gemm_kernel<false><<<dim3(H / 64, TB / 128), 256, 0, stream>>>(
        z, Wk, nullptr, nullptr, keys, B * S, H, H);

    // full recurrence in one persistent kernel (grid barrier between steps)
    lstm_persistent<<<256, 512, 0, stream>>>(gates_ih, W_hh, Hseq, bar);

    // Q = Hseq @ Wq^T
    gemm_kernel<true><<<dim3(H / 64, TB / 128), 256, 0, stream>>>(
        Hseq, Wq, nullptr, nullptr, Qbuf, TB, H, H);

    // attention fused: scores+softmax+context+U
    attn_fused<<<TB, 256, 0, stream>>>(Qbuf, keys, z, v_att, Hseq, Ubuf);

    // split-precision conversions (U first: Bconv overlay clobbers nothing live)
    conv_split<<<1024, 256, 0, stream>>>(Ubuf, Aconv, (long)TB * 256);
    conv_split<<<2048, 256, 0, stream>>>(W_proj, Bconv, (long)V * 256);

    // logits = U @ W_proj^T + b_proj via split-bf16 MFMA, direct [B,T,V] write
    gemm_mfma_proj<<<4000, 256, 0, stream>>>(Aconv, Bconv, b_proj, out);
}

// Round 4
// 2457.054 us; speedup vs baseline: 4.3959x; 4.3959x over previous
//
#include <hip/hip_runtime.h>
#include <hip/hip_bf16.h>
#include <cstddef>

// Problem dims (fixed by the reference)
constexpr int B = 32, T = 128, S = 128, D = 512, H = 512, V = 16000;
constexpr int G4H = 4 * H;     // 2048
constexpr int TB = T * B;      // 4096

typedef __bf16 bf16x8 __attribute__((ext_vector_type(8)));
typedef float  f32x4  __attribute__((ext_vector_type(4)));

__device__ __forceinline__ float tanh_fast(float x) {
    return 1.0f - 2.0f / (__expf(2.0f * x) + 1.0f);
}
__device__ __forceinline__ float sigmoid_fast(float x) {
    return 1.0f / (1.0f + __expf(-x));
}
__device__ __forceinline__ unsigned short f2bf_rn(float x) {
    unsigned u = __float_as_uint(x);
    unsigned r = (u + 0x7FFFu + ((u >> 16) & 1u)) >> 16;
    return (unsigned short)r;
}
__device__ __forceinline__ float bf2f(unsigned short h) {
    return __uint_as_float(((unsigned)h) << 16);
}
__device__ __forceinline__ void async16(const void* g, void* l) {
    __builtin_amdgcn_global_load_lds(
        (const __attribute__((address_space(1))) void*)g,
        (__attribute__((address_space(3))) void*)l, 16, 0, 0);
}

// ---------------------------------------------------------------------------
// Embedding gather
// ---------------------------------------------------------------------------
__global__ __launch_bounds__(128) void gather_emb(
    const int* __restrict__ x, const int* __restrict__ teacher,
    const float* __restrict__ embed, float* __restrict__ emb_g)
{
    int r = blockIdx.x;            // t*B + b
    int t = r >> 5, b = r & 31;
    int tok = (t == 0) ? x[b * T] : teacher[b * T + t - 1];
    const float4* src = (const float4*)(embed + (size_t)tok * D);
    float4* dst = (float4*)(emb_g + (size_t)r * D);
    dst[threadIdx.x] = src[threadIdx.x];
}

// ---------------------------------------------------------------------------
// Generic fp32 tiled GEMM (gates/keys/Q)
// ---------------------------------------------------------------------------
template<bool BT>
__global__ __launch_bounds__(256) void gemm_kernel(
    const float* __restrict__ A, const float* __restrict__ Bm,
    const float* __restrict__ bias1, const float* __restrict__ bias2,
    float* __restrict__ C, int M, int N, int K)
{
    constexpr int BM = 128, BN = 64, BK = 16;
    __shared__ float As[BK][BM + 4];
    __shared__ float Bs[BK][BN + 4];

    int tid = threadIdx.x;
    int m0 = blockIdx.y * BM, n0 = blockIdx.x * BN;
    int tx = tid & 15, ty = tid >> 4;
    int ar = tid >> 2;
    int ak = (tid & 3) * 4;
    int bkk = tid >> 4;
    int bnn = (tid & 15) * 4;

    float acc[8][4];
    #pragma unroll
    for (int i = 0; i < 8; ++i)
        #pragma unroll
        for (int j = 0; j < 4; ++j) acc[i][j] = 0.f;

    for (int k0 = 0; k0 < K; k0 += BK) {
        #pragma unroll
        for (int rr = 0; rr < 2; ++rr) {
            int row = ar + rr * 64;
            float4 v = *(const float4*)(A + (size_t)(m0 + row) * K + k0 + ak);
            As[ak + 0][row] = v.x; As[ak + 1][row] = v.y;
            As[ak + 2][row] = v.z; As[ak + 3][row] = v.w;
        }
        if (BT) {
            float4 v = *(const float4*)(Bm + (size_t)(n0 + ar) * K + k0 + ak);
            Bs[ak + 0][ar] = v.x; Bs[ak + 1][ar] = v.y;
            Bs[ak + 2][ar] = v.z; Bs[ak + 3][ar] = v.w;
        } else {
            float4 v = *(const float4*)(Bm + (size_t)(k0 + bkk) * N + n0 + bnn);
            *(float4*)&Bs[bkk][bnn] = v;
        }
        __syncthreads();

        #pragma unroll
        for (int kk = 0; kk < BK; ++kk) {
            float a[8], bb[4];
            *(float4*)&a[0] = *(const float4*)&As[kk][ty * 8];
            *(float4*)&a[4] = *(const float4*)&As[kk][ty * 8 + 4];
            *(float4*)&bb[0] = *(const float4*)&Bs[kk][tx * 4];
            #pragma unroll
            for (int i = 0; i < 8; ++i)
                #pragma unroll
                for (int j = 0; j < 4; ++j)
                    acc[i][j] = fmaf(a[i], bb[j], acc[i][j]);
        }
        __syncthreads();
    }

    float bs[4];
    #pragma unroll
    for (int j = 0; j < 4; ++j) {
        float v = 0.f;
        if (bias1) v += bias1[n0 + tx * 4 + j];
        if (bias2) v += bias2[n0 + tx * 4 + j];
        bs[j] = v;
    }
    #pragma unroll
    for (int i = 0; i < 8; ++i) {
        int row = m0 + ty * 8 + i;
        float* crow = C + (size_t)row * N;
        float4 o;
        o.x = acc[i][0] + bs[0]; o.y = acc[i][1] + bs[1];
        o.z = acc[i][2] + bs[2]; o.w = acc[i][3] + bs[3];
        *(float4*)(crow + n0 + tx * 4) = o;
    }
}

// ---------------------------------------------------------------------------
// LSTM step, one launch per t. Grid 256 blocks x 256 threads.
// Block bk owns h = {2bk, 2bk+1} -> 8 gate rows (g*512 + 2bk + hl).
// Thread (b = tid&31, r = tid>>5): holds h_{t-1}[b][r*64 .. r*64+64) in
// registers, computes partial dots for ALL 8 rows over its k-slice,
// 8-way LDS reduce, then 64 threads do the cell update.
// hx read directly from Hseq[t-1] (layout [t][b][h]); cx in [h][b].
// ---------------------------------------------------------------------------
__global__ __launch_bounds__(256) void lstm_step2(
    const float* __restrict__ gates_ih_t,  // [32][2048] slice for this t
    const float* __restrict__ W_hh,        // [2048][512]
    const float* __restrict__ Hprev,       // [32][512] slice (t-1), null if t==0
    float* __restrict__ Hcur,              // [32][512] slice (t)
    float* __restrict__ cx,                // [512][32]
    int first)
{
    __shared__ float part[8][8][32];   // [ksrc][row][b]
    __shared__ float g8[8][32];        // final gates [row][b]

    int tid = threadIdx.x, bk = blockIdx.x;
    int b = tid & 31, r = tid >> 5;
    int h0 = bk * 2;

    float acc[8] = {0.f, 0.f, 0.f, 0.f, 0.f, 0.f, 0.f, 0.f};
    if (!first) {
        float4 hreg[16];
        const float4* hp = (const float4*)(Hprev + (size_t)b * 512 + r * 64);
        #pragma unroll
        for (int j = 0; j < 16; ++j) hreg[j] = hp[j];
        #pragma unroll
        for (int rr = 0; rr < 8; ++rr) {
            int row = (rr >> 1) * 512 + h0 + (rr & 1);
            const float4* wp = (const float4*)(W_hh + (size_t)row * 512 + r * 64);
            float a0 = 0.f, a1 = 0.f, a2 = 0.f, a3 = 0.f;
            #pragma unroll
            for (int j = 0; j < 16; ++j) {
                float4 w = wp[j], x = hreg[j];
                a0 = fmaf(w.x, x.x, a0); a1 = fmaf(w.y, x.y, a1);
                a2 = fmaf(w.z, x.z, a2); a3 = fmaf(w.w, x.w, a3);
            }
            acc[rr] = (a0 + a1) + (a2 + a3);
        }
    }
    #pragma unroll
    for (int rr = 0; rr < 8; ++rr) part[r][rr][b] = acc[rr];
    __syncthreads();

    // final gate for row r (this thread's row), batch b
    float gate = gates_ih_t[(size_t)b * 2048 + (r >> 1) * 512 + h0 + (r & 1)];
    #pragma unroll
    for (int rs = 0; rs < 8; ++rs) gate += part[rs][r][b];
    g8[r][b] = gate;
    __syncthreads();

    if (tid < 64) {
        int hl = tid >> 5, bb = tid & 31;
        float gi = g8[0 + hl][bb];
        float gf = g8[2 + hl][bb];
        float gg = g8[4 + hl][bb];
        float go = g8[6 + hl][bb];
        float i_ = sigmoid_fast(gi), f_ = sigmoid_fast(gf), o_ = sigmoid_fast(go);
        float c_old = first ? 0.f : cx[(size_t)(h0 + hl) * 32 + bb];
        float c = fmaf(f_, c_old, i_ * tanh_fast(gg));
        cx[(size_t)(h0 + hl) * 32 + bb] = c;
        Hcur[(size_t)bb * 512 + h0 + hl] = o_ * tanh_fast(c);
    }
}

// ---------------------------------------------------------------------------
// Fused attention
// ---------------------------------------------------------------------------
__global__ __launch_bounds__(256) void attn_fused(
    const float* __restrict__ Q, const float* __restrict__ keys,
    const float* __restrict__ z, const float* __restrict__ v_att,
    const float* __restrict__ Hseq, float* __restrict__ U)
{
    __shared__ float qv[512], va[512], ph[256], sc[128], red[128];
    int r = blockIdx.x, b = r & 31, tid = threadIdx.x;

    if (tid < 128) ((float4*)qv)[tid] = ((const float4*)(Q + (size_t)r * H))[tid];
    else           ((float4*)va)[tid - 128] = ((const float4*)v_att)[tid - 128];
    __syncthreads();

    int s = tid >> 1, half = tid & 1;
    const float4* k4 = (const float4*)(keys + ((size_t)b * S + s) * H + half * 256);
    const float4* q4p = (const float4*)(qv + half * 256);
    const float4* v4p = (const float4*)(va + half * 256);
    float acc = 0.f;
    #pragma unroll 4
    for (int i = 0; i < 64; ++i) {
        float4 kv = k4[i], q4 = q4p[i], v4 = v4p[i];
        acc += tanh_fast(kv.x + q4.x) * v4.x + tanh_fast(kv.y + q4.y) * v4.y
             + tanh_fast(kv.z + q4.z) * v4.z + tanh_fast(kv.w + q4.w) * v4.w;
    }
    ph[tid] = acc;
    __syncthreads();
    if (tid < 128) { float v = ph[2 * tid] + ph[2 * tid + 1]; sc[tid] = v; red[tid] = v; }
    __syncthreads();
    for (int st = 64; st > 0; st >>= 1) {
        if (tid < st) red[tid] = fmaxf(red[tid], red[tid + st]);
        __syncthreads();
    }
    float mx = red[0];
    __syncthreads();
    if (tid < 128) { float e = __expf(sc[tid] - mx); sc[tid] = e; red[tid] = e; }
    __syncthreads();
    for (int st = 64; st > 0; st >>= 1) {
        if (tid < st) red[tid] += red[tid + st];
        __syncthreads();
    }
    float inv = 1.0f / red[0];

    const float* zb = z + (size_t)b * S * H;
    int h1 = tid, h2 = tid + 256;
    float c1 = 0.f, c2 = 0.f;
    #pragma unroll 4
    for (int s2 = 0; s2 < S; ++s2) {
        float wgt = sc[s2];
        c1 = fmaf(wgt, zb[(size_t)s2 * H + h1], c1);
        c2 = fmaf(wgt, zb[(size_t)s2 * H + h2], c2);
    }
    float* urow = U + (size_t)r * (2 * H);
    urow[h1] = c1 * inv;
    urow[h2] = c2 * inv;
    urow[H + h1] = Hseq[(size_t)r * H + h1];
    urow[H + h2] = Hseq[(size_t)r * H + h2];
}

// ---------------------------------------------------------------------------
// fp32 -> split bf16 (hi|lo): src [rows][1024] f32 -> dst [rows][2048] bf16
// ---------------------------------------------------------------------------
__global__ __launch_bounds__(256) void conv_split(
    const float* __restrict__ src, unsigned short* __restrict__ dst, long total4)
{
    for (long i = (long)blockIdx.x * 256 + threadIdx.x; i < total4;
         i += (long)gridDim.x * 256) {
        long rr = i >> 8; int c4 = (int)(i & 255) * 4;
        float4 v = ((const float4*)src)[i];
        ushort4 h, l;
        h.x = f2bf_rn(v.x); l.x = f2bf_rn(v.x - bf2f(h.x));
        h.y = f2bf_rn(v.y); l.y = f2bf_rn(v.y - bf2f(h.y));
        h.z = f2bf_rn(v.z); l.z = f2bf_rn(v.z - bf2f(h.z));
        h.w = f2bf_rn(v.w); l.w = f2bf_rn(v.w - bf2f(h.w));
        *(ushort4*)(dst + rr * 2048 + c4) = h;
        *(ushort4*)(dst + rr * 2048 + 1024 + c4) = l;
    }
}

// ---------------------------------------------------------------------------
// bf16 MFMA projection GEMM, split-precision slabs (K_logical = 3072).
// ---------------------------------------------------------------------------
__global__ __launch_bounds__(256) void gemm_mfma_proj(
    const unsigned short* __restrict__ Ab,   // [4096][2048] bf16 bits
    const unsigned short* __restrict__ Bb,   // [16000][2048] bf16 bits
    const float* __restrict__ bias, float* __restrict__ out)
{
    __shared__ unsigned short As[128 * 32];
    __shared__ unsigned short Bs[128 * 32];

    int tid = threadIdx.x;
    int wid = tid >> 6, lane = tid & 63;
    int wm = wid >> 1, wn = wid & 1;
    int lr = lane & 15, lk = lane >> 4;

    int wg = blockIdx.x;                       // 4000 blocks = 8 * 500
    int swz = (wg & 7) * 500 + (wg >> 3);      // XCD-contiguous chunks
    int m_t = swz & 31, n_t = swz >> 5;        // n-major
    int m0 = m_t * 128, n0 = n_t * 128;

    f32x4 acc[4][4] = {};

    int crow = lane >> 2;
    int ccol = (lane & 3) * 8;

    for (int kt = 0; kt < 96; ++kt) {
        int k0 = kt * 32;
        int kA = (k0 < 2048) ? k0 : k0 - 2048;
        int kB = (k0 < 1024) ? k0 : k0 - 1024;
        #pragma unroll
        for (int c = 0; c < 2; ++c) {
            int ch = wid * 2 + c;
            int row = ch * 16 + crow;
            const unsigned short* ga = Ab + (size_t)(m0 + row) * 2048 + kA + ccol;
            async16(ga, &As[ch * 512]);
            const unsigned short* gb = Bb + (size_t)(n0 + row) * 2048 + kB + ccol;
            async16(gb, &Bs[ch * 512]);
        }
        __syncthreads();

        bf16x8 a[4], bfr[4];
        #pragma unroll
        for (int f = 0; f < 4; ++f) {
            a[f]   = *(const bf16x8*)&As[(wm * 64 + f * 16 + lr) * 32 + lk * 8];
            bfr[f] = *(const bf16x8*)&Bs[(wn * 64 + f * 16 + lr) * 32 + lk * 8];
        }
        #pragma unroll
        for (int i = 0; i < 4; ++i)
            #pragma unroll
            for (int j = 0; j < 4; ++j)
                acc[i][j] = __builtin_amdgcn_mfma_f32_16x16x32_bf16(
                    a[i], bfr[j], acc[i][j], 0, 0, 0);
        __syncthreads();
    }

    #pragma unroll
    for (int j = 0; j < 4; ++j) {
        int col = n0 + wn * 64 + j * 16 + lr;
        float bv = bias[col];
        #pragma unroll
        for (int i = 0; i < 4; ++i) {
            #pragma unroll
            for (int q = 0; q < 4; ++q) {
                int row = m0 + wm * 64 + i * 16 + lk * 4 + q;   // r = t*32+b
                int t = row >> 5, b = row & 31;
                out[((size_t)b * 128 + t) * 16000 + col] = acc[i][j][q] + bv;
            }
        }
    }
}

// ---------------------------------------------------------------------------
extern "C" void kernel_launch(void* const* d_in, const int* in_sizes, int n_in,
                              void* d_out, int out_size, void* d_ws, size_t ws_size,
                              hipStream_t stream)
{
    const int*   x       = (const int*)  d_in[0];
    const int*   teacher = (const int*)  d_in[1];
    const float* z       = (const float*)d_in[2];
    const float* embed   = (const float*)d_in[3];
    const float* W_ih    = (const float*)d_in[4];
    const float* b_ih    = (const float*)d_in[5];
    const float* W_hh    = (const float*)d_in[6];
    const float* b_hh    = (const float*)d_in[7];
    const float* Wq      = (const float*)d_in[8];
    const float* Wk      = (const float*)d_in[9];
    const float* v_att   = (const float*)d_in[10];
    const float* W_proj  = (const float*)d_in[11];
    const float* b_proj  = (const float*)d_in[12];
    float* out = (float*)d_out;

    // workspace layout (float offsets). Bconv overlays [0 .. 65.5MB) which is
    // dead (emb_g/gates_ih/keys/Qbuf/Hseq) by the time conv_split(W) runs.
    float* ws = (float*)d_ws;
    float* emb_g    = ws;                        // 2,097,152 f
    float* gates_ih = ws + 2097152;              // 8,388,608 f
    float* keys     = ws + 10485760;             // 2,097,152 f
    float* Qbuf     = ws + 12582912;             // 2,097,152 f
    float* Hseq     = ws + 14680064;             // 2,097,152 f
    float* Ubuf     = ws + 16777216;             // 4,194,304 f (ends 20,971,520)
    unsigned short* Aconv = (unsigned short*)(ws + 20971520);  // 16.8 MB
    unsigned short* Bconv = (unsigned short*)ws;               // 65.5 MB overlay
    float* cxbuf    = ws + 25165824;             // 16,384 f

    gather_emb<<<TB, 128, 0, stream>>>(x, teacher, embed, emb_g);

    // gates_ih = emb_g @ W_ih^T + (b_ih + b_hh)
    gemm_kernel<true><<<dim3(G4H / 64, TB / 128), 256, 0, stream>>>(
        emb_g, W_ih, b_ih, b_hh, gates_ih, TB, G4H, D);

    // keys = z @ Wk
    gemm_kernel<false><<<dim3(H / 64, TB / 128), 256, 0, stream>>>(
        z, Wk, nullptr, nullptr, keys, B * S, H, H);

    // sequential LSTM recurrence: one small launch per step
    for (int t = 0; t < T; ++t) {
        const float* hprev = (t == 0) ? nullptr : Hseq + (size_t)(t - 1) * B * H;
        lstm_step2<<<256, 256, 0, stream>>>(
            gates_ih + (size_t)t * B * G4H, W_hh, hprev,
            Hseq + (size_t)t * B * H, cxbuf, t == 0 ? 1 : 0);
    }

    // Q = Hseq @ Wq^T
    gemm_kernel<true><<<dim3(H / 64, TB / 128), 256, 0, stream>>>(
        Hseq, Wq, nullptr, nullptr, Qbuf, TB, H, H);

    // attention fused: scores+softmax+context+U
    attn_fused<<<TB, 256, 0, stream>>>(Qbuf, keys, z, v_att, Hseq, Ubuf);

    // split-precision conversions (U first: Bconv overlay clobbers nothing live)
    conv_split<<<1024, 256, 0, stream>>>(Ubuf, Aconv, (long)TB * 256);
    conv_split<<<2048, 256, 0, stream>>>(W_proj, Bconv, (long)V * 256);

    // logits = U @ W_proj^T + b_proj via split-bf16 MFMA, direct [B,T,V] write
    gemm_mfma_proj<<<4000, 256, 0, stream>>>(Aconv, Bconv, b_proj, out);
}